// Round 1
// baseline (20284.825 us; speedup 1.0000x reference)
//
#include <hip/hip_runtime.h>
#include <hip/hip_bf16.h>
#include <hip/hip_fp16.h>

#define SEQ   4096
#define IDIM  2048
#define HDIM  2048
#define G4    8192
#define NBLK  256
#define NREP  8      // message replicas (r8 optimum): 32 readers/line, 24-unit publish

typedef __attribute__((ext_vector_type(8))) short short8;   // 8 x bf16 (4 VGPRs)
typedef __attribute__((ext_vector_type(4))) float f32x4;    // MFMA accumulator

// ---------------- numerics (v_exp2 / v_rcp based, ~1e-6 rel err) ----------------
__device__ __forceinline__ float fast_sig(float x) {
    float e = __builtin_amdgcn_exp2f(-1.4426950408889634f * x);   // exp(-x)
    return __builtin_amdgcn_rcpf(1.0f + e);
}
__device__ __forceinline__ float fast_tanh(float x) {
    float e = __builtin_amdgcn_exp2f(2.8853900817779268f * x);    // exp(2x)
    return 1.0f - 2.0f * __builtin_amdgcn_rcpf(e + 1.0f);
}
__device__ __forceinline__ unsigned short f2h(float f) {
    __half h = __float2half_rn(f);
    union { __half h; unsigned short s; } c; c.h = h; return c.s;
}
__device__ __forceinline__ float h2f(unsigned short u) {
    union { unsigned short s; __half h; } c; c.s = u; return __half2float(c.h);
}

// ---------------- phase 1: xg = x @ Wih^T + bias, bf16 MFMA ---------------------
// C[s,g] = sum_k x[s,k] * Wih[g,k]. A-frag = x rows, B-frag = Wih rows (B[k][n] =
// Wih[n][k]) -> both frags are 8 consecutive k of one row: identical
// ds_read_b128 pattern from row-major LDS tiles. Layouts per guide (m89/m91/
// m120): A/B lane L <-> [L&15][(L>>4)*8+j]; D lane L reg r <-> row=(L>>4)*4+r,
// col=L&15. fp32 global loads converted to bf16 during staging.
#define GM 128
#define GN 128
#define GK 32
#define APAD 40   // row pad: 80 B rows keep 16B alignment; 2-way LDS conflict (free)

__global__ __launch_bounds__(256, 2)
void xg_gemm(const float* __restrict__ x, const float* __restrict__ Wih,
             const float* __restrict__ bih, const float* __restrict__ bhh,
             __hip_bfloat16* __restrict__ xg)
{
    __shared__ __hip_bfloat16 As[GM][APAD];   // 10.25 KB
    __shared__ __hip_bfloat16 Bs[GN][APAD];

    const int t  = threadIdx.x;
    const int g0 = blockIdx.x * GN;           // 64 tiles over G4
    const int s0 = blockIdx.y * GM;           // 32 tiles over SEQ
    const int w  = t >> 6, L = t & 63;
    const int quad = L >> 4, lane16 = L & 15;
    const int wm = w >> 1, wn = w & 1;        // wave grid 2x2, each 64x64

    f32x4 acc[4][4];
#pragma unroll
    for (int mt = 0; mt < 4; ++mt)
#pragma unroll
        for (int nt = 0; nt < 4; ++nt) acc[mt][nt] = (f32x4){0.f, 0.f, 0.f, 0.f};

    const int srow = t >> 1, shalf = t & 1;   // staging: 128 rows x 2 halves of 16
    const float* xp = x   + (size_t)(s0 + srow) * IDIM + 16 * shalf;
    const float* wp = Wih + (size_t)(g0 + srow) * IDIM + 16 * shalf;

    for (int k0 = 0; k0 < IDIM; k0 += GK) {
        float4 a0 = *(const float4*)(xp + k0);
        float4 a1 = *(const float4*)(xp + k0 + 4);
        float4 a2 = *(const float4*)(xp + k0 + 8);
        float4 a3 = *(const float4*)(xp + k0 + 12);
        float4 b0 = *(const float4*)(wp + k0);
        float4 b1 = *(const float4*)(wp + k0 + 4);
        float4 b2 = *(const float4*)(wp + k0 + 8);
        float4 b3 = *(const float4*)(wp + k0 + 12);
        __syncthreads();
        {
            union { __hip_bfloat16 h[8]; uint4 u; } pk;
            pk.h[0]=__float2bfloat16(a0.x); pk.h[1]=__float2bfloat16(a0.y);
            pk.h[2]=__float2bfloat16(a0.z); pk.h[3]=__float2bfloat16(a0.w);
            pk.h[4]=__float2bfloat16(a1.x); pk.h[5]=__float2bfloat16(a1.y);
            pk.h[6]=__float2bfloat16(a1.z); pk.h[7]=__float2bfloat16(a1.w);
            *(uint4*)&As[srow][16 * shalf] = pk.u;
            pk.h[0]=__float2bfloat16(a2.x); pk.h[1]=__float2bfloat16(a2.y);
            pk.h[2]=__float2bfloat16(a2.z); pk.h[3]=__float2bfloat16(a2.w);
            pk.h[4]=__float2bfloat16(a3.x); pk.h[5]=__float2bfloat16(a3.y);
            pk.h[6]=__float2bfloat16(a3.z); pk.h[7]=__float2bfloat16(a3.w);
            *(uint4*)&As[srow][16 * shalf + 8] = pk.u;
            pk.h[0]=__float2bfloat16(b0.x); pk.h[1]=__float2bfloat16(b0.y);
            pk.h[2]=__float2bfloat16(b0.z); pk.h[3]=__float2bfloat16(b0.w);
            pk.h[4]=__float2bfloat16(b1.x); pk.h[5]=__float2bfloat16(b1.y);
            pk.h[6]=__float2bfloat16(b1.z); pk.h[7]=__float2bfloat16(b1.w);
            *(uint4*)&Bs[srow][16 * shalf] = pk.u;
            pk.h[0]=__float2bfloat16(b2.x); pk.h[1]=__float2bfloat16(b2.y);
            pk.h[2]=__float2bfloat16(b2.z); pk.h[3]=__float2bfloat16(b2.w);
            pk.h[4]=__float2bfloat16(b3.x); pk.h[5]=__float2bfloat16(b3.y);
            pk.h[6]=__float2bfloat16(b3.z); pk.h[7]=__float2bfloat16(b3.w);
            *(uint4*)&Bs[srow][16 * shalf + 8] = pk.u;
        }
        __syncthreads();

        short8 af[4], bf[4];
#pragma unroll
        for (int mt = 0; mt < 4; ++mt)
            af[mt] = *(const short8*)&As[wm * 64 + mt * 16 + lane16][quad * 8];
#pragma unroll
        for (int nt = 0; nt < 4; ++nt)
            bf[nt] = *(const short8*)&Bs[wn * 64 + nt * 16 + lane16][quad * 8];
#pragma unroll
        for (int mt = 0; mt < 4; ++mt)
#pragma unroll
            for (int nt = 0; nt < 4; ++nt)
                acc[mt][nt] = __builtin_amdgcn_mfma_f32_16x16x32_bf16(
                                  af[mt], bf[nt], acc[mt][nt], 0, 0, 0);
    }

#pragma unroll
    for (int nt = 0; nt < 4; ++nt) {
        const int g = g0 + wn * 64 + nt * 16 + lane16;
        const float bias = bih[g] + bhh[g];
#pragma unroll
        for (int mt = 0; mt < 4; ++mt) {
#pragma unroll
            for (int r = 0; r < 4; ++r) {
                const int so = s0 + wm * 64 + mt * 16 + quad * 4 + r;
                xg[(size_t)so * G4 + g] = __float2bfloat16(acc[mt][nt][r] + bias);
            }
        }
    }
}

// ---------------- phase 2: persistent LSTM recurrence --------------------------
// 256 blocks x 256 threads, 1 block/CU. Block b owns h indices [8b, 8b+8).
// Wave w = gate w. Lane L: rg=L>>4, cg=L&15. Transport = r8's best (NREP=8 fused
// {tag:16, 3x fp16} units, atomic-exchange publish, parity double-buffer) with
// r10's chunked streaming consume (flag-gated chunks, barrier A deleted).
//
// Round-11: LATENCY SHAVE on the serial chain (MfmaUtil 0, VALUBusy 15.6%,
// HBM 1.4% -> purely round-trip bound at ~8700 cy/step):
// (a) depth-2 PIPELINED POLL: issue the next poll set before checking the
//     current one. A blocking do{load}while has period ~= full agent-load
//     latency, so expected discovery = lat + lat/2; with one set in flight the
//     period halves -> discovery ~= lat + lat/4. sched_barrier(0) pins the
//     prefetch loads above the check so the compiler can't sink them.
// (b) CHUNK ROTATION: wave w consumes chunks in order w, w+1, w+2, w+3 (mod 4)
//     so it starts on its OWN staged chunk (ready by construction) while late
//     producers drain (~1-2us publish-burst spread). Done via wave-uniform
//     switch(w) so wv[] indexing stays compile-time (runtime-indexed register
//     arrays -> scratch).
// (c) xgl write hoisted off the post-barrier critical path (xgl is wave0-
//     private through LDS: writers t<32 and readers t<8 are both wave 0, so
//     in-wave program order suffices; no barrier involvement needed).
// Overwrite safety unchanged: hsh parity (wave c can reach staging(s+2) only
// after ALL blocks published s+1, which transitively requires every wave of
// this block to have passed barrierB(s) and hence finished its step-s reads of
// hsh[s&1]); msg parity (observing tag s from all producers => all blocks
// finished staging s-1, i.e. done reading parity-(s-1) units).
__global__ __launch_bounds__(256, 1)
void lstm_rec(const float* __restrict__ Whh,
              const __hip_bfloat16* __restrict__ xg,
              float* __restrict__ hout,                 // [HDIM] final h (fp32)
              unsigned long long* __restrict__ msg)     // [2][NREP][3][NBLK], zeroed
{
    __shared__ float hsh[2][HDIM];   // 16 KB, parity double-buffer
    __shared__ float gsum[4][8];
    __shared__ float xgl[32];
    __shared__ float hloc[8];
    __shared__ int   flag[4];        // chunk-ready step markers

    const int t  = threadIdx.x;
    const int b  = blockIdx.x;
    const int w  = t >> 6;
    const int L  = t & 63;
    const int rg = L >> 4;
    const int cg = L & 15;
    const int rb = b & (NREP - 1);   // replica this block polls

    float4 wv[2][32];
#pragma unroll
    for (int mp = 0; mp < 2; ++mp) {
        const float* rp = Whh + (size_t)(w * HDIM + 8 * b + 2 * rg + mp) * HDIM + 4 * cg;
#pragma unroll
        for (int j = 0; j < 32; ++j) wv[mp][j] = *(const float4*)(rp + 64 * j);
    }

    if (t < 4) flag[t] = -1;
    float creg = 0.0f;               // cell state (t<8 only)
    float xval = 0.0f;
    if (t < 32)
        xval = __bfloat162float(xg[(size_t)(t >> 3) * HDIM + 8 * b + (t & 7)]);  // s=0
    __syncthreads();                 // flag init visible

    for (int s = 0; s < SEQ; ++s) {
        const int pb = s & 1;

        // ---- stage chunk w of h_s into hsh[pb] (thread t <-> producer t) ----
        float f0,f1,f2,f3,f4,f5,f6,f7;
        if (s == 0) {
            f0=f1=f2=f3=f4=f5=f6=f7 = 0.0f;
        } else {
            const unsigned long long* p0 = &msg[(size_t)((pb * NREP + rb) * 3 + 0) * NBLK + t];
            const unsigned long long* p1 = &msg[(size_t)((pb * NREP + rb) * 3 + 1) * NBLK + t];
            const unsigned long long* p2 = &msg[(size_t)((pb * NREP + rb) * 3 + 2) * NBLK + t];
            const unsigned tgt = (unsigned)s;
            unsigned long long v0, v1, v2;
            v0 = __hip_atomic_load(p0, __ATOMIC_RELAXED, __HIP_MEMORY_SCOPE_AGENT);
            v1 = __hip_atomic_load(p1, __ATOMIC_RELAXED, __HIP_MEMORY_SCOPE_AGENT);
            v2 = __hip_atomic_load(p2, __ATOMIC_RELAXED, __HIP_MEMORY_SCOPE_AGENT);
            for (;;) {
                // depth-2: prefetch next set before checking the current set
                unsigned long long n0 = __hip_atomic_load(p0, __ATOMIC_RELAXED, __HIP_MEMORY_SCOPE_AGENT);
                unsigned long long n1 = __hip_atomic_load(p1, __ATOMIC_RELAXED, __HIP_MEMORY_SCOPE_AGENT);
                unsigned long long n2 = __hip_atomic_load(p2, __ATOMIC_RELAXED, __HIP_MEMORY_SCOPE_AGENT);
                __builtin_amdgcn_sched_barrier(0);   // keep prefetch above check
                if (!((unsigned)(v0 & 0xFFFFu) < tgt ||
                      (unsigned)(v1 & 0xFFFFu) < tgt ||
                      (unsigned)(v2 & 0xFFFFu) < tgt)) break;
                v0 = n0; v1 = n1; v2 = n2;
            }
            f0 = h2f((unsigned short)(v0 >> 16));
            f1 = h2f((unsigned short)(v0 >> 32));
            f2 = h2f((unsigned short)(v0 >> 48));
            f3 = h2f((unsigned short)(v1 >> 16));
            f4 = h2f((unsigned short)(v1 >> 32));
            f5 = h2f((unsigned short)(v1 >> 48));
            f6 = h2f((unsigned short)(v2 >> 16));
            f7 = h2f((unsigned short)(v2 >> 32));
        }
        float4 hv0 = { f0, f1, f2, f3 };
        float4 hv1 = { f4, f5, f6, f7 };
        *(float4*)&hsh[pb][8 * t]     = hv0;
        *(float4*)&hsh[pb][8 * t + 4] = hv1;
        if (L == 0)
            __hip_atomic_store(&flag[w], s, __ATOMIC_RELEASE, __HIP_MEMORY_SCOPE_WORKGROUP);

        if (t < 32) xgl[t] = xval;   // wave0-private via LDS; off the post-barrier path

        // ---- dot over 4 flag-gated chunks, rotated so own chunk goes first ----
        float a0 = 0.0f, a1 = 0.0f;
#define DOT_CHUNK(c, dowait)                                                   \
        do {                                                                   \
            if (dowait) {                                                      \
                while (__hip_atomic_load(&flag[(c)], __ATOMIC_ACQUIRE,         \
                                         __HIP_MEMORY_SCOPE_WORKGROUP) < s) {} \
            }                                                                  \
            _Pragma("unroll")                                                  \
            for (int j = 8 * (c); j < 8 * (c) + 8; ++j) {                      \
                float4 hv = *(const float4*)&hsh[pb][4 * (cg + 16 * j)];       \
                a0 += wv[0][j].x * hv.x; a0 += wv[0][j].y * hv.y;              \
                a0 += wv[0][j].z * hv.z; a0 += wv[0][j].w * hv.w;              \
                a1 += wv[1][j].x * hv.x; a1 += wv[1][j].y * hv.y;              \
                a1 += wv[1][j].z * hv.z; a1 += wv[1][j].w * hv.w;              \
            }                                                                  \
        } while (0)

        switch (w) {                 // wave-uniform branch; c stays compile-time
        case 0:  DOT_CHUNK(0, false); DOT_CHUNK(1, true);  DOT_CHUNK(2, true);  DOT_CHUNK(3, true);  break;
        case 1:  DOT_CHUNK(1, false); DOT_CHUNK(2, true);  DOT_CHUNK(3, true);  DOT_CHUNK(0, true);  break;
        case 2:  DOT_CHUNK(2, false); DOT_CHUNK(3, true);  DOT_CHUNK(0, true);  DOT_CHUNK(1, true);  break;
        default: DOT_CHUNK(3, false); DOT_CHUNK(0, true);  DOT_CHUNK(1, true);  DOT_CHUNK(2, true);  break;
        }
#undef DOT_CHUNK

#pragma unroll
        for (int mask = 1; mask <= 8; mask <<= 1) {        // reduce over cg
            a0 += __shfl_xor(a0, mask, 64);
            a1 += __shfl_xor(a1, mask, 64);
        }
        if (cg == 0) { gsum[w][2 * rg] = a0; gsum[w][2 * rg + 1] = a1; }
        __syncthreads();                                   // barrier B

        if (t < 8) {
            float pi = gsum[0][t] + xgl[t];
            float pf = gsum[1][t] + xgl[8 + t];
            float pg = gsum[2][t] + xgl[16 + t];
            float po = gsum[3][t] + xgl[24 + t];
            float c  = fast_sig(pf) * creg + fast_sig(pi) * fast_tanh(pg);
            creg = c;
            float h  = fast_sig(po) * fast_tanh(c);
            hloc[t] = h;
            if (s == SEQ - 1) hout[8 * b + t] = h;
        }

        if (s + 1 < SEQ) {
            const int p = (s + 1) & 1;
            // publish 3 units x NREP replicas via atomic swap (r8 pattern)
            if (t < 3 * NREP) {
                const int j = t % 3, r = t / 3;
                float u0 = hloc[3 * j], u1 = hloc[3 * j + 1];
                float u2 = (3 * j + 2 < 8) ? hloc[3 * j + 2] : 0.0f;
                unsigned long long u = (unsigned long long)(unsigned short)(s + 1)
                    | ((unsigned long long)f2h(u0) << 16)
                    | ((unsigned long long)f2h(u1) << 32)
                    | ((unsigned long long)f2h(u2) << 48);
                (void)__hip_atomic_exchange(
                        &msg[(size_t)((p * NREP + r) * 3 + j) * NBLK + b], u,
                        __ATOMIC_RELAXED, __HIP_MEMORY_SCOPE_AGENT);
            }
            // prefetch xg for s+1 (hidden under next iteration's poll)
            if (t < 32)
                xval = __bfloat162float(xg[(size_t)(s + 1) * G4 + (size_t)(t >> 3) * HDIM + 8 * b + (t & 7)]);
        }
    }
}

// ---------------- phase 3: out[o] = h . Wfc[o,:] + bfc[o] ----------------------
__global__ __launch_bounds__(64)
void fc_kernel(const float* __restrict__ h, const float* __restrict__ Wfc,
               const float* __restrict__ bfc, float* __restrict__ out)
{
    const int o = blockIdx.x;
    const int L = threadIdx.x;
    const float* wr = Wfc + (size_t)o * HDIM;
    float s = 0.0f;
#pragma unroll
    for (int jj = 0; jj < 8; ++jj) {
        float4 wvv = *(const float4*)(wr + 4 * (L + 64 * jj));
        float4 hv  = *(const float4*)(h  + 4 * (L + 64 * jj));
        s += wvv.x * hv.x + wvv.y * hv.y + wvv.z * hv.z + wvv.w * hv.w;
    }
#pragma unroll
    for (int mask = 1; mask <= 32; mask <<= 1) s += __shfl_xor(s, mask, 64);
    if (L == 0) out[o] = s + bfc[o];
}

// ---------------- launcher -----------------------------------------------------
extern "C" void kernel_launch(void* const* d_in, const int* in_sizes, int n_in,
                              void* d_out, int out_size, void* d_ws, size_t ws_size,
                              hipStream_t stream)
{
    (void)in_sizes; (void)n_in; (void)out_size; (void)ws_size;
    const float* x   = (const float*)d_in[0];
    const float* Wih = (const float*)d_in[1];
    const float* Whh = (const float*)d_in[2];
    const float* bih = (const float*)d_in[3];
    const float* bhh = (const float*)d_in[4];
    const float* Wfc = (const float*)d_in[5];
    const float* bfc = (const float*)d_in[6];
    float* out = (float*)d_out;

    // ws layout: xg bf16 [SEQ][G4] (64 MiB) | hout fp32 [HDIM] | msg u64 [2][NREP][3][NBLK]
    __hip_bfloat16* xg       = (__hip_bfloat16*)d_ws;
    float* hout              = (float*)((char*)d_ws + (size_t)SEQ * G4 * sizeof(__hip_bfloat16));
    unsigned long long* msg  = (unsigned long long*)(hout + HDIM);

    // ws is poisoned 0xAA before every launch -> tags would read as fresh; MUST zero.
    (void)hipMemsetAsync(msg, 0, (size_t)2 * NREP * 3 * NBLK * sizeof(unsigned long long), stream);

    dim3 g1(G4 / GN, SEQ / GM);  // (64, 32)
    hipLaunchKernelGGL(xg_gemm, g1, dim3(256), 0, stream, x, Wih, bih, bhh, xg);

    // lstm_rec needs all 256 blocks co-resident. Prefer the cooperative-launch
    // guarantee; if the API refuses, fall back to a plain launch: grid==256
    // with 1 block/CU on an idle 256-CU device is co-resident by construction.
    float* hout_arg = hout;
    unsigned long long* msg_arg = msg;
    void* args[] = { (void*)&Whh, (void*)&xg, (void*)&hout_arg, (void*)&msg_arg };
    hipError_t ce = hipLaunchCooperativeKernel((const void*)lstm_rec, dim3(NBLK), dim3(256),
                                               args, 0, stream);
    if (ce != hipSuccess) {
        hipLaunchKernelGGL(lstm_rec, dim3(NBLK), dim3(256), 0, stream, Whh, xg, hout, msg);
    }

    hipLaunchKernelGGL(fc_kernel, dim3(2048), dim3(64), 0, stream, hout, Wfc, bfc, out);
}

// Round 2
// 17108.424 us; speedup vs baseline: 1.1857x; 1.1857x over previous
//
#include <hip/hip_runtime.h>
#include <hip/hip_bf16.h>
#include <hip/hip_fp16.h>

#define SEQ   4096
#define IDIM  2048
#define HDIM  2048
#define G4    8192
#define NBLK  256
#define NREP  8      // message replicas (r8 optimum): 32 readers/line, 24-unit publish

typedef __attribute__((ext_vector_type(8))) short short8;   // 8 x bf16 (4 VGPRs)
typedef __attribute__((ext_vector_type(4))) float f32x4;    // MFMA accumulator

// ---------------- numerics (v_exp2 / v_rcp based, ~1e-6 rel err) ----------------
__device__ __forceinline__ float fast_sig(float x) {
    float e = __builtin_amdgcn_exp2f(-1.4426950408889634f * x);   // exp(-x)
    return __builtin_amdgcn_rcpf(1.0f + e);
}
__device__ __forceinline__ float fast_tanh(float x) {
    float e = __builtin_amdgcn_exp2f(2.8853900817779268f * x);    // exp(2x)
    return 1.0f - 2.0f * __builtin_amdgcn_rcpf(e + 1.0f);
}
__device__ __forceinline__ unsigned short f2h(float f) {
    __half h = __float2half_rn(f);
    union { __half h; unsigned short s; } c; c.h = h; return c.s;
}
__device__ __forceinline__ float h2f(unsigned short u) {
    union { unsigned short s; __half h; } c; c.s = u; return __half2float(c.h);
}

// ---------------- phase 1: xg = x @ Wih^T + bias, bf16 MFMA ---------------------
// C[s,g] = sum_k x[s,k] * Wih[g,k]. A-frag = x rows, B-frag = Wih rows (B[k][n] =
// Wih[n][k]) -> both frags are 8 consecutive k of one row: identical
// ds_read_b128 pattern from row-major LDS tiles. Layouts per guide (m89/m91/
// m120): A/B lane L <-> [L&15][(L>>4)*8+j]; D lane L reg r <-> row=(L>>4)*4+r,
// col=L&15. fp32 global loads converted to bf16 during staging.
#define GM 128
#define GN 128
#define GK 32
#define APAD 40   // row pad: 80 B rows keep 16B alignment; 2-way LDS conflict (free)

__global__ __launch_bounds__(256, 2)
void xg_gemm(const float* __restrict__ x, const float* __restrict__ Wih,
             const float* __restrict__ bih, const float* __restrict__ bhh,
             __hip_bfloat16* __restrict__ xg)
{
    __shared__ __hip_bfloat16 As[GM][APAD];   // 10.25 KB
    __shared__ __hip_bfloat16 Bs[GN][APAD];

    const int t  = threadIdx.x;
    const int g0 = blockIdx.x * GN;           // 64 tiles over G4
    const int s0 = blockIdx.y * GM;           // 32 tiles over SEQ
    const int w  = t >> 6, L = t & 63;
    const int quad = L >> 4, lane16 = L & 15;
    const int wm = w >> 1, wn = w & 1;        // wave grid 2x2, each 64x64

    f32x4 acc[4][4];
#pragma unroll
    for (int mt = 0; mt < 4; ++mt)
#pragma unroll
        for (int nt = 0; nt < 4; ++nt) acc[mt][nt] = (f32x4){0.f, 0.f, 0.f, 0.f};

    const int srow = t >> 1, shalf = t & 1;   // staging: 128 rows x 2 halves of 16
    const float* xp = x   + (size_t)(s0 + srow) * IDIM + 16 * shalf;
    const float* wp = Wih + (size_t)(g0 + srow) * IDIM + 16 * shalf;

    for (int k0 = 0; k0 < IDIM; k0 += GK) {
        float4 a0 = *(const float4*)(xp + k0);
        float4 a1 = *(const float4*)(xp + k0 + 4);
        float4 a2 = *(const float4*)(xp + k0 + 8);
        float4 a3 = *(const float4*)(xp + k0 + 12);
        float4 b0 = *(const float4*)(wp + k0);
        float4 b1 = *(const float4*)(wp + k0 + 4);
        float4 b2 = *(const float4*)(wp + k0 + 8);
        float4 b3 = *(const float4*)(wp + k0 + 12);
        __syncthreads();
        {
            union { __hip_bfloat16 h[8]; uint4 u; } pk;
            pk.h[0]=__float2bfloat16(a0.x); pk.h[1]=__float2bfloat16(a0.y);
            pk.h[2]=__float2bfloat16(a0.z); pk.h[3]=__float2bfloat16(a0.w);
            pk.h[4]=__float2bfloat16(a1.x); pk.h[5]=__float2bfloat16(a1.y);
            pk.h[6]=__float2bfloat16(a1.z); pk.h[7]=__float2bfloat16(a1.w);
            *(uint4*)&As[srow][16 * shalf] = pk.u;
            pk.h[0]=__float2bfloat16(a2.x); pk.h[1]=__float2bfloat16(a2.y);
            pk.h[2]=__float2bfloat16(a2.z); pk.h[3]=__float2bfloat16(a2.w);
            pk.h[4]=__float2bfloat16(a3.x); pk.h[5]=__float2bfloat16(a3.y);
            pk.h[6]=__float2bfloat16(a3.z); pk.h[7]=__float2bfloat16(a3.w);
            *(uint4*)&As[srow][16 * shalf + 8] = pk.u;
            pk.h[0]=__float2bfloat16(b0.x); pk.h[1]=__float2bfloat16(b0.y);
            pk.h[2]=__float2bfloat16(b0.z); pk.h[3]=__float2bfloat16(b0.w);
            pk.h[4]=__float2bfloat16(b1.x); pk.h[5]=__float2bfloat16(b1.y);
            pk.h[6]=__float2bfloat16(b1.z); pk.h[7]=__float2bfloat16(b1.w);
            *(uint4*)&Bs[srow][16 * shalf] = pk.u;
            pk.h[0]=__float2bfloat16(b2.x); pk.h[1]=__float2bfloat16(b2.y);
            pk.h[2]=__float2bfloat16(b2.z); pk.h[3]=__float2bfloat16(b2.w);
            pk.h[4]=__float2bfloat16(b3.x); pk.h[5]=__float2bfloat16(b3.y);
            pk.h[6]=__float2bfloat16(b3.z); pk.h[7]=__float2bfloat16(b3.w);
            *(uint4*)&Bs[srow][16 * shalf + 8] = pk.u;
        }
        __syncthreads();

        short8 af[4], bf[4];
#pragma unroll
        for (int mt = 0; mt < 4; ++mt)
            af[mt] = *(const short8*)&As[wm * 64 + mt * 16 + lane16][quad * 8];
#pragma unroll
        for (int nt = 0; nt < 4; ++nt)
            bf[nt] = *(const short8*)&Bs[wn * 64 + nt * 16 + lane16][quad * 8];
#pragma unroll
        for (int mt = 0; mt < 4; ++mt)
#pragma unroll
            for (int nt = 0; nt < 4; ++nt)
                acc[mt][nt] = __builtin_amdgcn_mfma_f32_16x16x32_bf16(
                                  af[mt], bf[nt], acc[mt][nt], 0, 0, 0);
    }

#pragma unroll
    for (int nt = 0; nt < 4; ++nt) {
        const int g = g0 + wn * 64 + nt * 16 + lane16;
        const float bias = bih[g] + bhh[g];
#pragma unroll
        for (int mt = 0; mt < 4; ++mt) {
#pragma unroll
            for (int r = 0; r < 4; ++r) {
                const int so = s0 + wm * 64 + mt * 16 + quad * 4 + r;
                xg[(size_t)so * G4 + g] = __float2bfloat16(acc[mt][nt][r] + bias);
            }
        }
    }
}

// ---------------- phase 2: persistent LSTM recurrence --------------------------
// 256 blocks x 256 threads, 1 block/CU. Block b owns h indices [8b, 8b+8).
// Wave w = gate w. Lane L: rg=L>>4, cg=L&15. Sync = r8's best (NREP=8 fused
// {tag:16, 3x fp16} units, atomic-exchange publish, parity double-buffer) +
// r10's chunked streaming consume (flag-gated chunks, barrier A deleted).
//
// Round-12: REVERT of r11's bundle (depth-2 pinned poll + chunk rotation),
// which regressed 48%. Post-mortem: (1) sched_barrier-pinned prefetch loads
// forced a vmcnt wait on the NEW loads before every tag check -> poll period
// grew to >= a full agent-load latency; (2) switch(w) rotation quadruplicated
// the dot body -> VGPR 196->256, and rotation cannot win anyway since every
// wave needs ALL chunks per step (max over chunks is invariant to order);
// (3) desynchronized waves' LDS streams drove SQ_LDS_BANK_CONFLICT 4.5x up.
// Kept from r11 only: xgl staging write hoisted before the dot (wave0-private
// LDS: writers t<32 and readers t<8 are both wave 0, program order suffices).
// Overwrite safety unchanged from r10: hsh parity (reads of s-2's buffer
// precede barrierB(s-2) < barrierB(s-1) < staging(s)); msg parity (observing
// tag s from all producers => all blocks passed stage(s-1), i.e. finished
// reading parity-(s-1) units).
__global__ __launch_bounds__(256, 1)
void lstm_rec(const float* __restrict__ Whh,
              const __hip_bfloat16* __restrict__ xg,
              float* __restrict__ hout,                 // [HDIM] final h (fp32)
              unsigned long long* __restrict__ msg)     // [2][NREP][3][NBLK], zeroed
{
    __shared__ float hsh[2][HDIM];   // 16 KB, parity double-buffer
    __shared__ float gsum[4][8];
    __shared__ float xgl[32];
    __shared__ float hloc[8];
    __shared__ int   flag[4];        // chunk-ready step markers

    const int t  = threadIdx.x;
    const int b  = blockIdx.x;
    const int w  = t >> 6;
    const int L  = t & 63;
    const int rg = L >> 4;
    const int cg = L & 15;
    const int rb = b & (NREP - 1);   // replica this block polls

    float4 wv[2][32];
#pragma unroll
    for (int mp = 0; mp < 2; ++mp) {
        const float* rp = Whh + (size_t)(w * HDIM + 8 * b + 2 * rg + mp) * HDIM + 4 * cg;
#pragma unroll
        for (int j = 0; j < 32; ++j) wv[mp][j] = *(const float4*)(rp + 64 * j);
    }

    if (t < 4) flag[t] = -1;
    float creg = 0.0f;               // cell state (t<8 only)
    float xval = 0.0f;
    if (t < 32)
        xval = __bfloat162float(xg[(size_t)(t >> 3) * HDIM + 8 * b + (t & 7)]);  // s=0
    __syncthreads();                 // flag init visible

    for (int s = 0; s < SEQ; ++s) {
        const int pb = s & 1;

        // ---- stage chunk w of h_s into hsh[pb] (thread t <-> producer t) ----
        float f0,f1,f2,f3,f4,f5,f6,f7;
        if (s == 0) {
            f0=f1=f2=f3=f4=f5=f6=f7 = 0.0f;
        } else {
            const unsigned long long* p0 = &msg[(size_t)((pb * NREP + rb) * 3 + 0) * NBLK + t];
            const unsigned long long* p1 = &msg[(size_t)((pb * NREP + rb) * 3 + 1) * NBLK + t];
            const unsigned long long* p2 = &msg[(size_t)((pb * NREP + rb) * 3 + 2) * NBLK + t];
            const unsigned tgt = (unsigned)s;
            unsigned long long v0, v1, v2;
            do {
                v0 = __hip_atomic_load(p0, __ATOMIC_RELAXED, __HIP_MEMORY_SCOPE_AGENT);
                v1 = __hip_atomic_load(p1, __ATOMIC_RELAXED, __HIP_MEMORY_SCOPE_AGENT);
                v2 = __hip_atomic_load(p2, __ATOMIC_RELAXED, __HIP_MEMORY_SCOPE_AGENT);
            } while ((unsigned)(v0 & 0xFFFFu) < tgt ||
                     (unsigned)(v1 & 0xFFFFu) < tgt ||
                     (unsigned)(v2 & 0xFFFFu) < tgt);
            f0 = h2f((unsigned short)(v0 >> 16));
            f1 = h2f((unsigned short)(v0 >> 32));
            f2 = h2f((unsigned short)(v0 >> 48));
            f3 = h2f((unsigned short)(v1 >> 16));
            f4 = h2f((unsigned short)(v1 >> 32));
            f5 = h2f((unsigned short)(v1 >> 48));
            f6 = h2f((unsigned short)(v2 >> 16));
            f7 = h2f((unsigned short)(v2 >> 32));
        }
        float4 hv0 = { f0, f1, f2, f3 };
        float4 hv1 = { f4, f5, f6, f7 };
        *(float4*)&hsh[pb][8 * t]     = hv0;
        *(float4*)&hsh[pb][8 * t + 4] = hv1;
        if (L == 0)
            __hip_atomic_store(&flag[w], s, __ATOMIC_RELEASE, __HIP_MEMORY_SCOPE_WORKGROUP);

        if (t < 32) xgl[t] = xval;   // wave0-private via LDS; off the post-barrier path

        // ---- dot over 4 flag-gated chunks ----
        float a0 = 0.0f, a1 = 0.0f;
#pragma unroll
        for (int c = 0; c < 4; ++c) {
            if (c != w) {
                while (__hip_atomic_load(&flag[c], __ATOMIC_ACQUIRE,
                                         __HIP_MEMORY_SCOPE_WORKGROUP) < s) {}
            }
#pragma unroll
            for (int j = 8 * c; j < 8 * c + 8; ++j) {
                float4 hv = *(const float4*)&hsh[pb][4 * (cg + 16 * j)];
                a0 += wv[0][j].x * hv.x; a0 += wv[0][j].y * hv.y;
                a0 += wv[0][j].z * hv.z; a0 += wv[0][j].w * hv.w;
                a1 += wv[1][j].x * hv.x; a1 += wv[1][j].y * hv.y;
                a1 += wv[1][j].z * hv.z; a1 += wv[1][j].w * hv.w;
            }
        }
#pragma unroll
        for (int mask = 1; mask <= 8; mask <<= 1) {        // reduce over cg
            a0 += __shfl_xor(a0, mask, 64);
            a1 += __shfl_xor(a1, mask, 64);
        }
        if (cg == 0) { gsum[w][2 * rg] = a0; gsum[w][2 * rg + 1] = a1; }
        __syncthreads();                                   // barrier B

        if (t < 8) {
            float pi = gsum[0][t] + xgl[t];
            float pf = gsum[1][t] + xgl[8 + t];
            float pg = gsum[2][t] + xgl[16 + t];
            float po = gsum[3][t] + xgl[24 + t];
            float c  = fast_sig(pf) * creg + fast_sig(pi) * fast_tanh(pg);
            creg = c;
            float h  = fast_sig(po) * fast_tanh(c);
            hloc[t] = h;
            if (s == SEQ - 1) hout[8 * b + t] = h;
        }

        if (s + 1 < SEQ) {
            const int p = (s + 1) & 1;
            // publish 3 units x NREP replicas via atomic swap (r8 pattern)
            if (t < 3 * NREP) {
                const int j = t % 3, r = t / 3;
                float u0 = hloc[3 * j], u1 = hloc[3 * j + 1];
                float u2 = (3 * j + 2 < 8) ? hloc[3 * j + 2] : 0.0f;
                unsigned long long u = (unsigned long long)(unsigned short)(s + 1)
                    | ((unsigned long long)f2h(u0) << 16)
                    | ((unsigned long long)f2h(u1) << 32)
                    | ((unsigned long long)f2h(u2) << 48);
                (void)__hip_atomic_exchange(
                        &msg[(size_t)((p * NREP + r) * 3 + j) * NBLK + b], u,
                        __ATOMIC_RELAXED, __HIP_MEMORY_SCOPE_AGENT);
            }
            // prefetch xg for s+1 (hidden under next iteration's poll)
            if (t < 32)
                xval = __bfloat162float(xg[(size_t)(s + 1) * G4 + (size_t)(t >> 3) * HDIM + 8 * b + (t & 7)]);
        }
    }
}

// ---------------- phase 3: out[o] = h . Wfc[o,:] + bfc[o] ----------------------
__global__ __launch_bounds__(64)
void fc_kernel(const float* __restrict__ h, const float* __restrict__ Wfc,
               const float* __restrict__ bfc, float* __restrict__ out)
{
    const int o = blockIdx.x;
    const int L = threadIdx.x;
    const float* wr = Wfc + (size_t)o * HDIM;
    float s = 0.0f;
#pragma unroll
    for (int jj = 0; jj < 8; ++jj) {
        float4 wvv = *(const float4*)(wr + 4 * (L + 64 * jj));
        float4 hv  = *(const float4*)(h  + 4 * (L + 64 * jj));
        s += wvv.x * hv.x + wvv.y * hv.y + wvv.z * hv.z + wvv.w * hv.w;
    }
#pragma unroll
    for (int mask = 1; mask <= 32; mask <<= 1) s += __shfl_xor(s, mask, 64);
    if (L == 0) out[o] = s + bfc[o];
}

// ---------------- launcher -----------------------------------------------------
extern "C" void kernel_launch(void* const* d_in, const int* in_sizes, int n_in,
                              void* d_out, int out_size, void* d_ws, size_t ws_size,
                              hipStream_t stream)
{
    (void)in_sizes; (void)n_in; (void)out_size; (void)ws_size;
    const float* x   = (const float*)d_in[0];
    const float* Wih = (const float*)d_in[1];
    const float* Whh = (const float*)d_in[2];
    const float* bih = (const float*)d_in[3];
    const float* bhh = (const float*)d_in[4];
    const float* Wfc = (const float*)d_in[5];
    const float* bfc = (const float*)d_in[6];
    float* out = (float*)d_out;

    // ws layout: xg bf16 [SEQ][G4] (64 MiB) | hout fp32 [HDIM] | msg u64 [2][NREP][3][NBLK]
    __hip_bfloat16* xg       = (__hip_bfloat16*)d_ws;
    float* hout              = (float*)((char*)d_ws + (size_t)SEQ * G4 * sizeof(__hip_bfloat16));
    unsigned long long* msg  = (unsigned long long*)(hout + HDIM);

    // ws is poisoned 0xAA before every launch -> tags would read as fresh; MUST zero.
    (void)hipMemsetAsync(msg, 0, (size_t)2 * NREP * 3 * NBLK * sizeof(unsigned long long), stream);

    dim3 g1(G4 / GN, SEQ / GM);  // (64, 32)
    hipLaunchKernelGGL(xg_gemm, g1, dim3(256), 0, stream, x, Wih, bih, bhh, xg);

    // lstm_rec needs all 256 blocks co-resident. Prefer the cooperative-launch
    // guarantee; if the API refuses, fall back to a plain launch: grid==256
    // with 1 block/CU on an idle 256-CU device is co-resident by construction.
    float* hout_arg = hout;
    unsigned long long* msg_arg = msg;
    void* args[] = { (void*)&Whh, (void*)&xg, (void*)&hout_arg, (void*)&msg_arg };
    hipError_t ce = hipLaunchCooperativeKernel((const void*)lstm_rec, dim3(NBLK), dim3(256),
                                               args, 0, stream);
    if (ce != hipSuccess) {
        hipLaunchKernelGGL(lstm_rec, dim3(NBLK), dim3(256), 0, stream, Whh, xg, hout, msg);
    }

    hipLaunchKernelGGL(fc_kernel, dim3(2048), dim3(64), 0, stream, hout, Wfc, bfc, out);
}

// Round 3
// 11693.575 us; speedup vs baseline: 1.7347x; 1.4631x over previous
//
#include <hip/hip_runtime.h>
#include <hip/hip_bf16.h>
#include <hip/hip_fp16.h>

#define SEQ   4096
#define IDIM  2048
#define HDIM  2048
#define G4    8192
#define NBLK  256
#define NREP  8      // message replicas: rb=b&7 aligns replica r with XCD r (b%8 dispatch)

typedef __attribute__((ext_vector_type(8))) short short8;   // 8 x bf16 (4 VGPRs)
typedef __attribute__((ext_vector_type(4))) float f32x4;    // MFMA accumulator

// ---------------- numerics (v_exp2 / v_rcp based, ~1e-6 rel err) ----------------
__device__ __forceinline__ float fast_sig(float x) {
    float e = __builtin_amdgcn_exp2f(-1.4426950408889634f * x);   // exp(-x)
    return __builtin_amdgcn_rcpf(1.0f + e);
}
__device__ __forceinline__ float fast_tanh(float x) {
    float e = __builtin_amdgcn_exp2f(2.8853900817779268f * x);    // exp(2x)
    return 1.0f - 2.0f * __builtin_amdgcn_rcpf(e + 1.0f);
}
__device__ __forceinline__ unsigned short f2h(float f) {
    __half h = __float2half_rn(f);
    union { __half h; unsigned short s; } c; c.h = h; return c.s;
}
__device__ __forceinline__ float h2f(unsigned short u) {
    union { unsigned short s; __half h; } c; c.s = u; return __half2float(c.h);
}

// ---------------- phase 1: xg = x @ Wih^T + bias, bf16 MFMA ---------------------
#define GM 128
#define GN 128
#define GK 32
#define APAD 40   // row pad: 80 B rows keep 16B alignment; 2-way LDS conflict (free)

__global__ __launch_bounds__(256, 2)
void xg_gemm(const float* __restrict__ x, const float* __restrict__ Wih,
             const float* __restrict__ bih, const float* __restrict__ bhh,
             __hip_bfloat16* __restrict__ xg)
{
    __shared__ __hip_bfloat16 As[GM][APAD];   // 10.25 KB
    __shared__ __hip_bfloat16 Bs[GN][APAD];

    const int t  = threadIdx.x;
    const int g0 = blockIdx.x * GN;           // 64 tiles over G4
    const int s0 = blockIdx.y * GM;           // 32 tiles over SEQ
    const int w  = t >> 6, L = t & 63;
    const int quad = L >> 4, lane16 = L & 15;
    const int wm = w >> 1, wn = w & 1;        // wave grid 2x2, each 64x64

    f32x4 acc[4][4];
#pragma unroll
    for (int mt = 0; mt < 4; ++mt)
#pragma unroll
        for (int nt = 0; nt < 4; ++nt) acc[mt][nt] = (f32x4){0.f, 0.f, 0.f, 0.f};

    const int srow = t >> 1, shalf = t & 1;   // staging: 128 rows x 2 halves of 16
    const float* xp = x   + (size_t)(s0 + srow) * IDIM + 16 * shalf;
    const float* wp = Wih + (size_t)(g0 + srow) * IDIM + 16 * shalf;

    for (int k0 = 0; k0 < IDIM; k0 += GK) {
        float4 a0 = *(const float4*)(xp + k0);
        float4 a1 = *(const float4*)(xp + k0 + 4);
        float4 a2 = *(const float4*)(xp + k0 + 8);
        float4 a3 = *(const float4*)(xp + k0 + 12);
        float4 b0 = *(const float4*)(wp + k0);
        float4 b1 = *(const float4*)(wp + k0 + 4);
        float4 b2 = *(const float4*)(wp + k0 + 8);
        float4 b3 = *(const float4*)(wp + k0 + 12);
        __syncthreads();
        {
            union { __hip_bfloat16 h[8]; uint4 u; } pk;
            pk.h[0]=__float2bfloat16(a0.x); pk.h[1]=__float2bfloat16(a0.y);
            pk.h[2]=__float2bfloat16(a0.z); pk.h[3]=__float2bfloat16(a0.w);
            pk.h[4]=__float2bfloat16(a1.x); pk.h[5]=__float2bfloat16(a1.y);
            pk.h[6]=__float2bfloat16(a1.z); pk.h[7]=__float2bfloat16(a1.w);
            *(uint4*)&As[srow][16 * shalf] = pk.u;
            pk.h[0]=__float2bfloat16(a2.x); pk.h[1]=__float2bfloat16(a2.y);
            pk.h[2]=__float2bfloat16(a2.z); pk.h[3]=__float2bfloat16(a2.w);
            pk.h[4]=__float2bfloat16(a3.x); pk.h[5]=__float2bfloat16(a3.y);
            pk.h[6]=__float2bfloat16(a3.z); pk.h[7]=__float2bfloat16(a3.w);
            *(uint4*)&As[srow][16 * shalf + 8] = pk.u;
            pk.h[0]=__float2bfloat16(b0.x); pk.h[1]=__float2bfloat16(b0.y);
            pk.h[2]=__float2bfloat16(b0.z); pk.h[3]=__float2bfloat16(b0.w);
            pk.h[4]=__float2bfloat16(b1.x); pk.h[5]=__float2bfloat16(b1.y);
            pk.h[6]=__float2bfloat16(b1.z); pk.h[7]=__float2bfloat16(b1.w);
            *(uint4*)&Bs[srow][16 * shalf] = pk.u;
            pk.h[0]=__float2bfloat16(b2.x); pk.h[1]=__float2bfloat16(b2.y);
            pk.h[2]=__float2bfloat16(b2.z); pk.h[3]=__float2bfloat16(b2.w);
            pk.h[4]=__float2bfloat16(b3.x); pk.h[5]=__float2bfloat16(b3.y);
            pk.h[6]=__float2bfloat16(b3.z); pk.h[7]=__float2bfloat16(b3.w);
            *(uint4*)&Bs[srow][16 * shalf + 8] = pk.u;
        }
        __syncthreads();

        short8 af[4], bf[4];
#pragma unroll
        for (int mt = 0; mt < 4; ++mt)
            af[mt] = *(const short8*)&As[wm * 64 + mt * 16 + lane16][quad * 8];
#pragma unroll
        for (int nt = 0; nt < 4; ++nt)
            bf[nt] = *(const short8*)&Bs[wn * 64 + nt * 16 + lane16][quad * 8];
#pragma unroll
        for (int mt = 0; mt < 4; ++mt)
#pragma unroll
            for (int nt = 0; nt < 4; ++nt)
                acc[mt][nt] = __builtin_amdgcn_mfma_f32_16x16x32_bf16(
                                  af[mt], bf[nt], acc[mt][nt], 0, 0, 0);
    }

#pragma unroll
    for (int nt = 0; nt < 4; ++nt) {
        const int g = g0 + wn * 64 + nt * 16 + lane16;
        const float bias = bih[g] + bhh[g];
#pragma unroll
        for (int mt = 0; mt < 4; ++mt) {
#pragma unroll
            for (int r = 0; r < 4; ++r) {
                const int so = s0 + wm * 64 + mt * 16 + quad * 4 + r;
                xg[(size_t)so * G4 + g] = __float2bfloat16(acc[mt][nt][r] + bias);
            }
        }
    }
}

// ---------------- phase 2: persistent LSTM recurrence --------------------------
// Round-13 restructure: WAVE-OWNS-H-COLUMNS. 256 blocks x 256 threads, 1/CU.
// Block b owns h[8b..8b+8); wave w owns h indices {8b+2w, 8b+2w+1} across ALL
// 4 gates (8 weight rows/wave). Lane L holds the k-slice k=4L+256jj (jj=0..7)
// of all 8 rows -> each hsh float4 read is reused 8x: 8 ds_read_b128/thread
// (was 32) => LDS-pipe time in the dot ~4x down. After a 10-shfl fold
// butterfly (lane L ends with total of row L&7; row = 4bit2+2bit1+bit0 =
// (gate<<1)|hi) + 3 gather shfls, every lane holds all 4 gate pre-activations
// for its hi=L&1 -> gate math, c-state and publish are fully IN-WAVE.
// Deleted: barrier B, gsum, hloc, xgl, t<8 serialization. No block-wide sync
// in the loop (only LDS chunk flags).
// Transport: 4 units/block (one per wave: {tag:16, h0:16, h1:16}) x NREP
// replicas, atomic-exchange publish, parity double-buffer. Consumer thread t
// polls all 4 units of producer t (parallel loads). NREP=8 keeps replica r on
// XCD r (rb=b&7, dispatch b%8).
// Overwrite safety WITHOUT barrier B: per-wave program order (dot(s-2) reads
// -> publish(s-1), data-dependent) + every consumer checks all 4 units of its
// producer, so observing tag s from producer P implies ALL P's waves staged
// s-1, i.e. finished reading every block's parity-(s-1) msg units and its own
// hsh[(s-2)&1]. Two-parity double-buffer closes both hazards as in r10.
__global__ __launch_bounds__(256, 1)
void lstm_rec(const float* __restrict__ Whh,
              const __hip_bfloat16* __restrict__ xg,
              float* __restrict__ hout,                 // [HDIM] final h (fp32)
              unsigned long long* __restrict__ msg)     // [2][NREP][4][NBLK], zeroed
{
    __shared__ float hsh[2][HDIM];   // 16 KB, parity double-buffer
    __shared__ int   flag[4];        // chunk-ready step markers

    const int t  = threadIdx.x;
    const int b  = blockIdx.x;
    const int w  = t >> 6;
    const int L  = t & 63;
    const int hi = L & 1;            // which of the wave's 2 h-indices this lane tracks
    const int go = (L >> 1) & 3;     // own gate slot after the fold (row = L&7 = 2*go+hi)
    const int rb = b & (NREP - 1);   // replica this block polls

    // 8 rows: r=0..7 <-> gate g=r>>1, hi=r&1; global row (r>>1)*HDIM + 8b+2w+(r&1).
    // Lane L holds k = 4L + 256*jj, jj=0..7 (coalesced float4 per (r,jj)).
    float4 wv[8][8];
#pragma unroll
    for (int r = 0; r < 8; ++r) {
        const float* rp = Whh + (size_t)((r >> 1) * HDIM + 8 * b + 2 * w + (r & 1)) * HDIM + 4 * L;
#pragma unroll
        for (int jj = 0; jj < 8; ++jj) wv[r][jj] = *(const float4*)(rp + 256 * jj);
    }

    if (t < 4) flag[t] = -1;
    float creg = 0.0f;               // cell state for h(8b+2w+hi), per lane
    // xg pre-activations for s=0: xq[G] = xg[0][G*HDIM + 8b+2w+hi]
    float xq0, xq1, xq2, xq3;
    {
        const size_t xb = (size_t)(8 * b + 2 * w + hi);
        xq0 = __bfloat162float(xg[xb]);
        xq1 = __bfloat162float(xg[xb + HDIM]);
        xq2 = __bfloat162float(xg[xb + 2 * HDIM]);
        xq3 = __bfloat162float(xg[xb + 3 * HDIM]);
    }
    __syncthreads();                 // flag init visible

    for (int s = 0; s < SEQ; ++s) {
        const int pb = s & 1;

        // ---- stage chunk w of h_s into hsh[pb] (thread t <-> producer t) ----
        float f0,f1,f2,f3,f4,f5,f6,f7;
        if (s == 0) {
            f0=f1=f2=f3=f4=f5=f6=f7 = 0.0f;
        } else {
            const unsigned long long* p0 = &msg[(size_t)((pb * NREP + rb) * 4 + 0) * NBLK + t];
            const unsigned long long* p1 = &msg[(size_t)((pb * NREP + rb) * 4 + 1) * NBLK + t];
            const unsigned long long* p2 = &msg[(size_t)((pb * NREP + rb) * 4 + 2) * NBLK + t];
            const unsigned long long* p3 = &msg[(size_t)((pb * NREP + rb) * 4 + 3) * NBLK + t];
            const unsigned tgt = (unsigned)s;
            unsigned long long v0, v1, v2, v3;
            do {
                v0 = __hip_atomic_load(p0, __ATOMIC_RELAXED, __HIP_MEMORY_SCOPE_AGENT);
                v1 = __hip_atomic_load(p1, __ATOMIC_RELAXED, __HIP_MEMORY_SCOPE_AGENT);
                v2 = __hip_atomic_load(p2, __ATOMIC_RELAXED, __HIP_MEMORY_SCOPE_AGENT);
                v3 = __hip_atomic_load(p3, __ATOMIC_RELAXED, __HIP_MEMORY_SCOPE_AGENT);
            } while ((unsigned)(v0 & 0xFFFFu) < tgt ||
                     (unsigned)(v1 & 0xFFFFu) < tgt ||
                     (unsigned)(v2 & 0xFFFFu) < tgt ||
                     (unsigned)(v3 & 0xFFFFu) < tgt);
            f0 = h2f((unsigned short)(v0 >> 16));
            f1 = h2f((unsigned short)(v0 >> 32));
            f2 = h2f((unsigned short)(v1 >> 16));
            f3 = h2f((unsigned short)(v1 >> 32));
            f4 = h2f((unsigned short)(v2 >> 16));
            f5 = h2f((unsigned short)(v2 >> 32));
            f6 = h2f((unsigned short)(v3 >> 16));
            f7 = h2f((unsigned short)(v3 >> 32));
        }
        float4 hv0 = { f0, f1, f2, f3 };
        float4 hv1 = { f4, f5, f6, f7 };
        *(float4*)&hsh[pb][8 * t]     = hv0;
        *(float4*)&hsh[pb][8 * t + 4] = hv1;
        if (L == 0)
            __hip_atomic_store(&flag[w], s, __ATOMIC_RELEASE, __HIP_MEMORY_SCOPE_WORKGROUP);

        // ---- dot: 8 rows share each hv; 8 ds_read_b128/thread, flag-gated ----
        float a0=0.f,a1=0.f,a2=0.f,a3=0.f,a4=0.f,a5=0.f,a6=0.f,a7=0.f;
#pragma unroll
        for (int c = 0; c < 4; ++c) {
            if (c != w) {
                while (__hip_atomic_load(&flag[c], __ATOMIC_ACQUIRE,
                                         __HIP_MEMORY_SCOPE_WORKGROUP) < s) {}
            }
#pragma unroll
            for (int u = 0; u < 2; ++u) {
                const int jj = 2 * c + u;
                float4 hv = *(const float4*)&hsh[pb][4 * (L + 64 * jj)];
                a0 += wv[0][jj].x*hv.x; a0 += wv[0][jj].y*hv.y; a0 += wv[0][jj].z*hv.z; a0 += wv[0][jj].w*hv.w;
                a1 += wv[1][jj].x*hv.x; a1 += wv[1][jj].y*hv.y; a1 += wv[1][jj].z*hv.z; a1 += wv[1][jj].w*hv.w;
                a2 += wv[2][jj].x*hv.x; a2 += wv[2][jj].y*hv.y; a2 += wv[2][jj].z*hv.z; a2 += wv[2][jj].w*hv.w;
                a3 += wv[3][jj].x*hv.x; a3 += wv[3][jj].y*hv.y; a3 += wv[3][jj].z*hv.z; a3 += wv[3][jj].w*hv.w;
                a4 += wv[4][jj].x*hv.x; a4 += wv[4][jj].y*hv.y; a4 += wv[4][jj].z*hv.z; a4 += wv[4][jj].w*hv.w;
                a5 += wv[5][jj].x*hv.x; a5 += wv[5][jj].y*hv.y; a5 += wv[5][jj].z*hv.z; a5 += wv[5][jj].w*hv.w;
                a6 += wv[6][jj].x*hv.x; a6 += wv[6][jj].y*hv.y; a6 += wv[6][jj].z*hv.z; a6 += wv[6][jj].w*hv.w;
                a7 += wv[7][jj].x*hv.x; a7 += wv[7][jj].y*hv.y; a7 += wv[7][jj].z*hv.z; a7 += wv[7][jj].w*hv.w;
            }
        }

        // ---- fold butterfly: lane L ends with total of row L&7 (10 shfls) ----
        float b0v = (hi ? a1 : a0) + __shfl_xor(hi ? a0 : a1, 1, 64);
        float b1v = (hi ? a3 : a2) + __shfl_xor(hi ? a2 : a3, 1, 64);
        float b2v = (hi ? a5 : a4) + __shfl_xor(hi ? a4 : a5, 1, 64);
        float b3v = (hi ? a7 : a6) + __shfl_xor(hi ? a6 : a7, 1, 64);
        const int bit1 = (L >> 1) & 1;
        float c0v = (bit1 ? b1v : b0v) + __shfl_xor(bit1 ? b0v : b1v, 2, 64);
        float c1v = (bit1 ? b3v : b2v) + __shfl_xor(bit1 ? b2v : b3v, 2, 64);
        const int bit2 = (L >> 2) & 1;
        float dv  = (bit2 ? c1v : c0v) + __shfl_xor(bit2 ? c0v : c1v, 4, 64);
        dv += __shfl_xor(dv, 8, 64);
        dv += __shfl_xor(dv, 16, 64);
        dv += __shfl_xor(dv, 32, 64);

        // ---- gather all 4 gates for this lane's hi (3 shfls + selects) ----
        // q_k = row (L&7)^(2k) = gate go^k, same hi. sorted[G] = q[G^go].
        float q0 = dv;
        float q1 = __shfl_xor(dv, 2, 64);
        float q2 = __shfl_xor(dv, 4, 64);
        float q3 = __shfl_xor(dv, 6, 64);
        float t0 = (go & 1) ? q1 : q0, t1 = (go & 1) ? q0 : q1;
        float t2 = (go & 1) ? q3 : q2, t3 = (go & 1) ? q2 : q3;
        float pi = ((go & 2) ? t2 : t0) + xq0;
        float pf = ((go & 2) ? t3 : t1) + xq1;
        float pg = ((go & 2) ? t0 : t2) + xq2;
        float po = ((go & 2) ? t1 : t3) + xq3;

        // ---- gates, in every lane (redundant across lane-groups, no LDS) ----
        float cn = fast_sig(pf) * creg + fast_sig(pi) * fast_tanh(pg);
        creg = cn;
        float h = fast_sig(po) * fast_tanh(cn);
        if (s == SEQ - 1 && L < 2) hout[8 * b + 2 * w + L] = h;

        if (s + 1 < SEQ) {
            const int p = (s + 1) & 1;
            float h0 = __shfl(h, 0, 64);   // hi=0 value of this wave
            float h1 = __shfl(h, 1, 64);   // hi=1 value
            if (L < NREP) {
                unsigned long long u = (unsigned long long)(unsigned short)(s + 1)
                    | ((unsigned long long)f2h(h0) << 16)
                    | ((unsigned long long)f2h(h1) << 32);
                (void)__hip_atomic_exchange(
                        &msg[(size_t)((p * NREP + L) * 4 + w) * NBLK + b], u,
                        __ATOMIC_RELAXED, __HIP_MEMORY_SCOPE_AGENT);
            }
            // prefetch xg for s+1 (hidden under next iteration's poll)
            const size_t xb = (size_t)(s + 1) * G4 + 8 * b + 2 * w + hi;
            xq0 = __bfloat162float(xg[xb]);
            xq1 = __bfloat162float(xg[xb + HDIM]);
            xq2 = __bfloat162float(xg[xb + 2 * HDIM]);
            xq3 = __bfloat162float(xg[xb + 3 * HDIM]);
        }
    }
}

// ---------------- phase 3: out[o] = h . Wfc[o,:] + bfc[o] ----------------------
__global__ __launch_bounds__(64)
void fc_kernel(const float* __restrict__ h, const float* __restrict__ Wfc,
               const float* __restrict__ bfc, float* __restrict__ out)
{
    const int o = blockIdx.x;
    const int L = threadIdx.x;
    const float* wr = Wfc + (size_t)o * HDIM;
    float s = 0.0f;
#pragma unroll
    for (int jj = 0; jj < 8; ++jj) {
        float4 wvv = *(const float4*)(wr + 4 * (L + 64 * jj));
        float4 hv  = *(const float4*)(h  + 4 * (L + 64 * jj));
        s += wvv.x * hv.x + wvv.y * hv.y + wvv.z * hv.z + wvv.w * hv.w;
    }
#pragma unroll
    for (int mask = 1; mask <= 32; mask <<= 1) s += __shfl_xor(s, mask, 64);
    if (L == 0) out[o] = s + bfc[o];
}

// ---------------- launcher -----------------------------------------------------
extern "C" void kernel_launch(void* const* d_in, const int* in_sizes, int n_in,
                              void* d_out, int out_size, void* d_ws, size_t ws_size,
                              hipStream_t stream)
{
    (void)in_sizes; (void)n_in; (void)out_size; (void)ws_size;
    const float* x   = (const float*)d_in[0];
    const float* Wih = (const float*)d_in[1];
    const float* Whh = (const float*)d_in[2];
    const float* bih = (const float*)d_in[3];
    const float* bhh = (const float*)d_in[4];
    const float* Wfc = (const float*)d_in[5];
    const float* bfc = (const float*)d_in[6];
    float* out = (float*)d_out;

    // ws layout: xg bf16 [SEQ][G4] (64 MiB) | hout fp32 [HDIM] | msg u64 [2][NREP][4][NBLK]
    __hip_bfloat16* xg       = (__hip_bfloat16*)d_ws;
    float* hout              = (float*)((char*)d_ws + (size_t)SEQ * G4 * sizeof(__hip_bfloat16));
    unsigned long long* msg  = (unsigned long long*)(hout + HDIM);

    // ws is poisoned 0xAA before every launch -> tags would read as fresh; MUST zero.
    (void)hipMemsetAsync(msg, 0, (size_t)2 * NREP * 4 * NBLK * sizeof(unsigned long long), stream);

    dim3 g1(G4 / GN, SEQ / GM);  // (64, 32)
    hipLaunchKernelGGL(xg_gemm, g1, dim3(256), 0, stream, x, Wih, bih, bhh, xg);

    // lstm_rec needs all 256 blocks co-resident. Prefer the cooperative-launch
    // guarantee; if the API refuses, fall back to a plain launch: grid==256
    // with 1 block/CU on an idle 256-CU device is co-resident by construction.
    float* hout_arg = hout;
    unsigned long long* msg_arg = msg;
    void* args[] = { (void*)&Whh, (void*)&xg, (void*)&hout_arg, (void*)&msg_arg };
    hipError_t ce = hipLaunchCooperativeKernel((const void*)lstm_rec, dim3(NBLK), dim3(256),
                                               args, 0, stream);
    if (ce != hipSuccess) {
        hipLaunchKernelGGL(lstm_rec, dim3(NBLK), dim3(256), 0, stream, Whh, xg, hout, msg);
    }

    hipLaunchKernelGGL(fc_kernel, dim3(2048), dim3(64), 0, stream, hout, Wfc, bfc, out);
}